// Round 8
// baseline (177.861 us; speedup 1.0000x reference)
//
#include <hip/hip_runtime.h>

#define B_ 8
#define N_ 8192
#define S_ 2048
#define D_ 256
#define EPS_ 1e-8f

/* ---------------- 1-D x-sort parameters ---------------- */
#define NBX   256
#define XMIN_ (-4.0f)
#define INVW_ 32.0f            /* bin width 1/32 over [-4,4) */
#define CUMP  258              /* cum array padded to even u16 count */

/* workspace layout (bytes) */
#define WS_SID  (B_*S_*16)                 /* wpts: 262144 */
#define WS_CUM  (WS_SID + B_*S_*2)         /* wsid: +32768 = 294912 */
#define WS_QID  (WS_CUM + B_*CUMP*2)       /* wcum: +4128 = 299040 */
#define WS_NEED (WS_QID + B_*N_*2)         /* wqid: +131072 = 430112 */

#define QW 8                               /* queries per wave (8 slots each) */
#define QBLK 32                            /* queries per 256-thr block */

/* ---------------- brute-force fallback params (proven R2 path) ----- */
#define TILE_Q 64
#define NTHR 512
#define NCH 8
#define CHUNK (S_/NCH)
#define HALF (CHUNK/2)

// Branchless stable top-3 insert (float + index), med3 network. Sorted
// invariant d0<=d1<=d2. Strict '<': incumbent wins ties. 12 VALU ops —
// 2.4x cheaper than the u64-composite network it replaces in the knn
// hot loop (R8). Ordering on exact float-key ties between DISTINCT points
// is visit-order dependent, but such ties are measure-zero on continuous
// random data (argument already relied on since R7's position-based ids).
__device__ __forceinline__ void insert3(float dd, int s,
                                        float& d0, float& d1, float& d2,
                                        int& i0, int& i1, int& i2) {
    bool ca = dd < d0;
    bool cb = dd < d1;
    bool cc = dd < d2;
    int i2n = cb ? i1 : (cc ? s : i2);
    int i1n = ca ? i0 : (cb ? s : i1);
    int i0n = ca ? s : i0;
    d2 = fminf(d2, fmaxf(d1, dd));
    d1 = __builtin_amdgcn_fmed3f(d0, d1, dd);
    d0 = fminf(d0, dd);
    i0 = i0n; i1 = i1n; i2 = i2n;
}

// Value-only top-3 insert (4 ops) — for the d3ub probe, which needs no
// indices. MERGE DISCIPLINE (R3 lesson) still applies: per-lane
// accumulators stay private for the whole search (slot classes are
// disjoint); the probe merges COPIES into discarded temps; exactly one
// destructive index-carrying slot merge at the end.
__device__ __forceinline__ void ins3v(float x, float& d0, float& d1, float& d2) {
    d2 = fminf(d2, fmaxf(d1, x));
    d1 = __builtin_amdgcn_fmed3f(d0, d1, x);
    d0 = fminf(d0, x);
}

/* ------------- prep: counting-sort candidates by bx, queries by ax ----- */
// (R5-proven logic; R8: 1024 threads for 4x faster stage/scatter, scan
// guarded to t<256.) blocks 0..7: candidates; 8..15: queries.
__global__ __launch_bounds__(1024) void prep_sort_kernel(
    const float* __restrict__ xyz1, const float* __restrict__ xyz2,
    float4* __restrict__ wpts, unsigned short* __restrict__ wsid,
    unsigned short* __restrict__ wcum, unsigned short* __restrict__ wqid)
{
    __shared__ unsigned int h[NBX];
    __shared__ unsigned int wsum[4];
    __shared__ unsigned char cbin[N_];
    const int blk = blockIdx.x, t = threadIdx.x, lane = t & 63, wv = t >> 6;

    const bool isq = blk >= B_;
    const int b = isq ? blk - B_ : blk;
    const int cnt = isq ? N_ : S_;
    const float* xs = isq ? (xyz1 + (size_t)b*3*N_) : (xyz2 + (size_t)b*3*S_);

    if (t < NBX) h[t] = 0;
    __syncthreads();
    for (int s = t; s < cnt; s += 1024) {
        float x = xs[s];
        int bin = min(NBX-1, max(0, (int)floorf((x - XMIN_) * INVW_)));
        cbin[s] = (unsigned char)bin;
        atomicAdd(&h[bin], 1u);
    }
    __syncthreads();
    unsigned int v = 0, incl = 0;
    if (t < NBX) {                       // waves 0..3 fully active (uniform)
        v = h[t];
        incl = v;
        #pragma unroll
        for (int off = 1; off < 64; off <<= 1) {
            unsigned int u = __shfl_up(incl, off);
            if (lane >= off) incl += u;
        }
        if (lane == 63) wsum[wv] = incl;
    }
    __syncthreads();
    if (t < NBX) {
        unsigned int base = 0;
        for (int w = 0; w < wv; ++w) base += wsum[w];
        unsigned int excl = base + incl - v;
        h[t] = excl;
        if (!isq) {
            unsigned short* cum = wcum + (size_t)b * CUMP;
            cum[t] = (unsigned short)excl;
            if (t == 0) { cum[NBX] = (unsigned short)S_; cum[NBX+1] = (unsigned short)S_; }
        }
    }
    __syncthreads();
    if (!isq) {
        for (int s = t; s < S_; s += 1024) {
            unsigned int pos = atomicAdd(&h[cbin[s]], 1u);
            float bx = xs[s], by = xs[S_+s], bz = xs[2*S_+s];
            float nn = fmaf(bz, bz, fmaf(by, by, bx*bx));   // proven fma order
            wpts[(size_t)b*S_ + pos] = make_float4(-2.f*bx, -2.f*by, -2.f*bz, nn);
            wsid[(size_t)b*S_ + pos] = (unsigned short)s;
        }
    } else {
        for (int s = t; s < N_; s += 1024) {
            unsigned int pos = atomicAdd(&h[cbin[s]], 1u);
            wqid[(size_t)b*N_ + pos] = (unsigned short)s;
        }
    }
}

/* ------ one-shot slab exact 3-NN + interpolation (8 slots/query) ------- */
// (R7-proven structure; R8: float accumulators.) 2048 blocks x 256 thr.
// Wave = 8 sorted queries x 8 slots; lane = qi*8 + slot. Per scan iter the
// 8 slots read 8 CONSECUTIVE float4s (128 contiguous bytes, broadcast to
// the 8 qi-groups). Schedule: scan(window +-128 rank) -> probe d3ub
// (value-only, temps discarded) -> slab = [cum[bin(ax-rad)],
// cum[bin(ax+rad)+1]) union over wave -> scan(slab \ window) -> single
// destructive index-carrying slot merge. Exactness: unscanned candidate =>
// bin outside slab => |bx-ax| > rad => dist^2 > d3ub + 1e-3 (margin >>
// fma rounding) => cannot enter or tie into the top-3. idx = sorted
// position (distinct keys on continuous data); remapped via wsid at end.
__global__ __launch_bounds__(256, 8) void knn8_kernel(
    const float* __restrict__ xyz1,
    const float4* __restrict__ wpts,
    const unsigned short* __restrict__ wsid,
    const unsigned short* __restrict__ wcum,
    const unsigned short* __restrict__ wqid,
    const float* __restrict__ points2,
    float* __restrict__ out)
{
    __shared__ float s_w[3][QBLK];
    __shared__ int   s_idx[3][QBLK];
    __shared__ int   s_oq[QBLK];

    const int b    = blockIdx.x & 7;             // batch-per-XCD swizzle
    const int qblk = blockIdx.x >> 3;
    const int t = threadIdx.x;
    const int wave = t >> 6, wl = t & 63;
    const int qi = wl >> 3, slot = wl & 7;
    const int row = wave * QW + qi;              // 0..31 within block

    const unsigned short* cum = wcum + (size_t)b * CUMP;
    const int q = wqid[(size_t)b * N_ + qblk * QBLK + row];
    const float* x1 = xyz1 + (size_t)b*3*N_;
    const float ax = x1[q], ay = x1[N_+q], az = x1[2*N_+q];
    const float n1a = fmaf(az, az, fmaf(ay, ay, ax*ax));
    const int qbin = min(NBX-1, max(0, (int)floorf((ax - XMIN_)*INVW_)));
    const int cq = cum[qbin];

    // wave-uniform window around this wave's 8 queries
    int cmin = cq, cmax = cq;
    #pragma unroll
    for (int off = 1; off < 64; off <<= 1) {
        cmin = min(cmin, __shfl_xor(cmin, off));
        cmax = max(cmax, __shfl_xor(cmax, off));
    }
    const int wlo = __builtin_amdgcn_readfirstlane(max(cmin - 128, 0));
    const int whi = __builtin_amdgcn_readfirstlane(min(cmax + 128, S_));

    const float4* pts4 = wpts + (size_t)b * S_;
    float d0 = __builtin_inff(), d1 = __builtin_inff(), d2 = __builtin_inff();
    int i0 = 0, i1 = 0, i2 = 0;

    auto scan = [&](int j0, int j1) {
        #pragma unroll 4
        for (int j = j0 + slot; j < j1; j += 8) {
            float4 p = pts4[j];
            float key = fmaf(ax, p.x, fmaf(ay, p.y, fmaf(az, p.z, p.w)));
            insert3(key, j, d0, d1, d2, i0, i1, i2);
        }
    };

    scan(wlo, whi);          // >=128 candidates seen by every query

    // ONE non-destructive probe: per-query d3 upper bound (value-only,
    // xor 1/2/4 spans the 8 slots; temps discarded)
    float r0 = d0, r1 = d1, r2 = d2;
    #pragma unroll
    for (int off = 1; off < 8; off <<= 1) {
        float s0 = __shfl_xor(r0, off);
        float s1 = __shfl_xor(r1, off);
        float s2 = __shfl_xor(r2, off);
        ins3v(s0, r0, r1, r2);
        ins3v(s1, r0, r1, r2);
        ins3v(s2, r0, r1, r2);
    }
    float rad = sqrtf(fmaxf(r2 + n1a + 1e-3f, 0.0f));
    int lob = min(NBX-1, max(0, (int)floorf((ax - rad - XMIN_)*INVW_)));
    int hib = min(NBX-1, max(0, (int)floorf((ax + rad - XMIN_)*INVW_)));
    int lo = cum[lob], hi = cum[hib + 1];

    // wave-uniform slab union
    int ulo = lo, uhi = hi;
    #pragma unroll
    for (int off = 1; off < 64; off <<= 1) {
        ulo = min(ulo, __shfl_xor(ulo, off));
        uhi = max(uhi, __shfl_xor(uhi, off));
    }
    ulo = __builtin_amdgcn_readfirstlane(ulo);
    uhi = __builtin_amdgcn_readfirstlane(uhi);

    // disjoint extensions (each j visited exactly once per query)
    scan(ulo, wlo);
    scan(whi, uhi);

    // single destructive slot merge (disjoint slot classes -> no dups;
    // equal keys across distinct points: measure-zero)
    #pragma unroll
    for (int off = 1; off < 8; off <<= 1) {
        float s0 = __shfl_xor(d0, off);
        float s1 = __shfl_xor(d1, off);
        float s2 = __shfl_xor(d2, off);
        int   j0 = __shfl_xor(i0, off);
        int   j1b = __shfl_xor(i1, off);
        int   j2b = __shfl_xor(i2, off);
        insert3(s0, j0,  d0, d1, d2, i0, i1, i2);
        insert3(s1, j1b, d0, d1, d2, i0, i1, i2);
        insert3(s2, j2b, d0, d1, d2, i0, i1, i2);
    }

    // epilogue: weights (proven arithmetic) + sorted-pos -> original id
    if (slot == 0) {
        const unsigned short* sid = wsid + (size_t)b * S_;
        float r0f = __fdiv_rn(1.0f, __fadd_rn(__fadd_rn(d0, n1a), EPS_));
        float r1f = __fdiv_rn(1.0f, __fadd_rn(__fadd_rn(d1, n1a), EPS_));
        float r2f = __fdiv_rn(1.0f, __fadd_rn(__fadd_rn(d2, n1a), EPS_));
        float rs = __fadd_rn(__fadd_rn(r0f, r1f), r2f);
        s_w[0][row] = __fdiv_rn(r0f, rs);
        s_w[1][row] = __fdiv_rn(r1f, rs);
        s_w[2][row] = __fdiv_rn(r2f, rs);
        s_idx[0][row] = sid[i0];
        s_idx[1][row] = sid[i1];
        s_idx[2][row] = sid[i2];
        s_oq[row] = q;
    }
    __syncthreads();

    // phase C: gather + weighted sum; 32 rows, 4 waves, 64 lanes x float4
    const float* p2 = points2 + (size_t)b * S_ * D_;
    for (int r = wave; r < QBLK; r += 4) {
        float w0 = s_w[0][r], w1 = s_w[1][r], w2 = s_w[2][r];
        float* op = out + ((size_t)b*N_ + s_oq[r]) * D_;
        const float4* f0 = (const float4*)(p2 + (size_t)s_idx[0][r]*D_) + wl;
        const float4* f1 = (const float4*)(p2 + (size_t)s_idx[1][r]*D_) + wl;
        const float4* f2 = (const float4*)(p2 + (size_t)s_idx[2][r]*D_) + wl;
        float4 v0 = *f0, v1 = *f1, v2v = *f2;
        float4 r4;
        r4.x = w0*v0.x + w1*v1.x + w2*v2v.x;
        r4.y = w0*v0.y + w1*v1.y + w2*v2v.y;
        r4.z = w0*v0.z + w1*v1.z + w2*v2v.z;
        r4.w = w0*v0.w + w1*v1.w + w2*v2v.w;
        *((float4*)op + wl) = r4;
    }
}

/* ---------------- brute-force fallback (proven R2 path) ------------- */
__global__ __launch_bounds__(NTHR, 8) void fp_brute_kernel(
    const float* __restrict__ xyz1,
    const float* __restrict__ xyz2,
    const float* __restrict__ points2,
    float* __restrict__ out)
{
    __shared__ float s_nn[S_] __attribute__((aligned(16)));
    __shared__ float s_pd[NCH][3][TILE_Q];
    __shared__ int   s_pi[NCH][3][TILE_Q];
    __shared__ float s_w[3][TILE_Q];
    __shared__ int   s_idx[3][TILE_Q];

    const int b  = blockIdx.x & 7;
    const int n0 = (blockIdx.x >> 3) * TILE_Q;
    const int t = threadIdx.x;
    const int wave = t >> 6, lane = t & 63;

    const float* x2 = xyz2 + (size_t)b * 3 * S_;
    for (int s = t; s < S_; s += NTHR) {
        float bx = x2[s], by = x2[S_ + s], bz = x2[2 * S_ + s];
        s_nn[s] = fmaf(bz, bz, fmaf(by, by, bx * bx));
    }
    __syncthreads();

    const int n = n0 + lane;
    const float* x1 = xyz1 + (size_t)b * 3 * N_;
    const float ax = x1[n], ay = x1[N_ + n], az = x1[2 * N_ + n];
    const float ax2 = -2.0f * ax, ay2 = -2.0f * ay, az2 = -2.0f * az;

    float a0 = __builtin_inff(), a1 = __builtin_inff(), a2 = __builtin_inff();
    int ja0 = 0, ja1 = 0, ja2 = 0;
    float c0 = __builtin_inff(), c1 = __builtin_inff(), c2 = __builtin_inff();
    int jc0 = 0, jc1 = 0, jc2 = 0;

    const int wu   = __builtin_amdgcn_readfirstlane(wave);
    const int sbeg = wu * CHUNK;
    const float* bxp = x2;
    const float* byp = x2 + S_;
    const float* bzp = x2 + 2 * S_;
    const float4* nn4 = (const float4*)s_nn;
    const int g0 = sbeg >> 2;
    #pragma unroll 2
    for (int g = 0; g < HALF / 4; ++g) {
        float4 nl = nn4[g0 + g];
        float4 nh = nn4[g0 + (HALF >> 2) + g];
        #pragma unroll
        for (int u = 0; u < 4; ++u) {
            const int sl = sbeg + 4 * g + u;
            const int sh = sl + HALF;
            float kl = fmaf(ax2, bxp[sl],
                       fmaf(ay2, byp[sl], fmaf(az2, bzp[sl], (&nl.x)[u])));
            float kh = fmaf(ax2, bxp[sh],
                       fmaf(ay2, byp[sh], fmaf(az2, bzp[sh], (&nh.x)[u])));
            insert3(kl, sl, a0, a1, a2, ja0, ja1, ja2);
            insert3(kh, sh, c0, c1, c2, jc0, jc1, jc2);
        }
    }
    insert3(c0, jc0, a0, a1, a2, ja0, ja1, ja2);
    insert3(c1, jc1, a0, a1, a2, ja0, ja1, ja2);
    insert3(c2, jc2, a0, a1, a2, ja0, ja1, ja2);

    s_pd[wave][0][lane] = a0; s_pd[wave][1][lane] = a1; s_pd[wave][2][lane] = a2;
    s_pi[wave][0][lane] = ja0; s_pi[wave][1][lane] = ja1; s_pi[wave][2][lane] = ja2;
    __syncthreads();

    if (t < TILE_Q) {
        float e0 = __builtin_inff(), e1 = __builtin_inff(), e2 = __builtin_inff();
        int j0 = 0, j1 = 0, j2 = 0;
        #pragma unroll
        for (int c = 0; c < NCH; ++c)
            #pragma unroll
            for (int k = 0; k < 3; ++k)
                insert3(s_pd[c][k][t], s_pi[c][k][t], e0, e1, e2, j0, j1, j2);
        const int nq = n0 + t;
        float qx = x1[nq], qy = x1[N_ + nq], qz = x1[2 * N_ + nq];
        float n1 = fmaf(qz, qz, fmaf(qy, qy, qx * qx));
        float r0 = __fdiv_rn(1.0f, __fadd_rn(__fadd_rn(e0, n1), EPS_));
        float r1 = __fdiv_rn(1.0f, __fadd_rn(__fadd_rn(e1, n1), EPS_));
        float r2 = __fdiv_rn(1.0f, __fadd_rn(__fadd_rn(e2, n1), EPS_));
        float rs = __fadd_rn(__fadd_rn(r0, r1), r2);
        s_w[0][t] = __fdiv_rn(r0, rs);
        s_w[1][t] = __fdiv_rn(r1, rs);
        s_w[2][t] = __fdiv_rn(r2, rs);
        s_idx[0][t] = j0; s_idx[1][t] = j1; s_idx[2][t] = j2;
    }
    __syncthreads();

    const float* p2 = points2 + (size_t)b * S_ * D_;
    float* op = out + ((size_t)b * N_ + n0) * D_;
    for (int qq = wave; qq < TILE_Q; qq += NCH) {
        float w0 = s_w[0][qq], w1 = s_w[1][qq], w2 = s_w[2][qq];
        const float4* f0 = (const float4*)(p2 + (size_t)s_idx[0][qq] * D_) + lane;
        const float4* f1 = (const float4*)(p2 + (size_t)s_idx[1][qq] * D_) + lane;
        const float4* f2 = (const float4*)(p2 + (size_t)s_idx[2][qq] * D_) + lane;
        float4 v0 = *f0, v1 = *f1, v2 = *f2;
        float4 r;
        r.x = w0 * v0.x + w1 * v1.x + w2 * v2.x;
        r.y = w0 * v0.y + w1 * v1.y + w2 * v2.y;
        r.z = w0 * v0.z + w1 * v1.z + w2 * v2.z;
        r.w = w0 * v0.w + w1 * v1.w + w2 * v2.w;
        *((float4*)(op + (size_t)qq * D_) + lane) = r;
    }
}

extern "C" void kernel_launch(void* const* d_in, const int* in_sizes, int n_in,
                              void* d_out, int out_size, void* d_ws, size_t ws_size,
                              hipStream_t stream) {
    const float* xyz1    = (const float*)d_in[0];
    const float* xyz2    = (const float*)d_in[1];
    // d_in[2] = points1 is unused by the reference output.
    const float* points2 = (const float*)d_in[3];
    float* out = (float*)d_out;

    if (d_ws && ws_size >= (size_t)WS_NEED) {
        float4*         wpts = (float4*)d_ws;
        unsigned short* wsid = (unsigned short*)((char*)d_ws + WS_SID);
        unsigned short* wcum = (unsigned short*)((char*)d_ws + WS_CUM);
        unsigned short* wqid = (unsigned short*)((char*)d_ws + WS_QID);
        prep_sort_kernel<<<dim3(2*B_), dim3(1024), 0, stream>>>(
            xyz1, xyz2, wpts, wsid, wcum, wqid);
        knn8_kernel<<<dim3(B_ * (N_/QBLK)), dim3(256), 0, stream>>>(
            xyz1, wpts, wsid, wcum, wqid, points2, out);
    } else {
        fp_brute_kernel<<<dim3(B_ * (N_ / TILE_Q)), dim3(NTHR), 0, stream>>>(
            xyz1, xyz2, points2, out);
    }
}

// Round 9
// 168.402 us; speedup vs baseline: 1.0562x; 1.0562x over previous
//
#include <hip/hip_runtime.h>

#define B_ 8
#define N_ 8192
#define S_ 2048
#define D_ 256
#define EPS_ 1e-8f

/* ---------------- 1-D x-sort parameters ---------------- */
#define NBX   256
#define XMIN_ (-4.0f)
#define INVW_ 32.0f            /* bin width 1/32 over [-4,4) */
#define CUMP  258              /* cum array padded to even u16 count */

/* workspace layout (bytes) */
#define WS_SID  (B_*S_*16)                 /* wpts: 262144 */
#define WS_CUM  (WS_SID + B_*S_*2)         /* wsid: +32768 = 294912 */
#define WS_QID  (WS_CUM + B_*CUMP*2)       /* wcum: +4128 = 299040 */
#define WS_NEED (WS_QID + B_*N_*2)         /* wqid: +131072 = 430112 */

#define QW 8                               /* queries per wave (8 slots each) */
#define QBLK 32                            /* queries per 256-thr block */

/* ---------------- brute-force fallback params (proven R2 path) ----- */
#define TILE_Q 64
#define NTHR 512
#define NCH 8
#define CHUNK (S_/NCH)
#define HALF (CHUNK/2)

// Branchless stable top-3 insert (float + index) — brute fallback only.
__device__ __forceinline__ void insert3(float dd, int s,
                                        float& d0, float& d1, float& d2,
                                        int& i0, int& i1, int& i2) {
    bool ca = dd < d0;
    bool cb = dd < d1;
    bool cc = dd < d2;
    int i2n = cb ? i1 : (cc ? s : i2);
    int i1n = ca ? i0 : (cb ? s : i1);
    int i0n = ca ? s : i0;
    d2 = fminf(d2, fmaxf(d1, dd));
    d1 = __builtin_amdgcn_fmed3f(d0, d1, dd);
    d0 = fminf(d0, dd);
    i0 = i0n; i1 = i1n; i2 = i2n;
}

// Top-3 insert on packed u64 composite (sortable(key)<<16 | pos).
// EMPIRICAL (R7 vs R8): this u64 form measured 60 us vs the float+index
// form's 72 us in the identical kernel — do not "optimize" it back.
// MERGE DISCIPLINE (R3 lesson): equal composites duplicate; only combine
// DISJOINT candidate sets; never re-reduce an already-merged result.
// Here: two per-lane chains over disjoint j-parity sets, merged once
// in-lane; probe merges COPIES into discarded temps; one destructive
// slot butterfly at the end.
__device__ __forceinline__ void ins3u64(unsigned long long x,
    unsigned long long& d0, unsigned long long& d1, unsigned long long& d2) {
    bool ca = x < d0, cb = x < d1, cc = x < d2;
    d2 = cb ? d1 : (cc ? x : d2);
    d1 = ca ? d0 : (cb ? x : d1);
    d0 = ca ? x : d0;
}

__device__ __forceinline__ unsigned long long packkey(float key, int j) {
    unsigned int kb = __float_as_uint(key);
    unsigned int sb = kb ^ ((unsigned int)((int)kb >> 31) | 0x80000000u);
    return ((unsigned long long)sb << 16) | (unsigned)j;
}

/* ------------- prep: counting-sort candidates by bx, queries by ax ----- */
// (R8-proven: 1024 threads saved ~12 us vs 256.) blocks 0..7: candidates;
// 8..15: queries.
__global__ __launch_bounds__(1024) void prep_sort_kernel(
    const float* __restrict__ xyz1, const float* __restrict__ xyz2,
    float4* __restrict__ wpts, unsigned short* __restrict__ wsid,
    unsigned short* __restrict__ wcum, unsigned short* __restrict__ wqid)
{
    __shared__ unsigned int h[NBX];
    __shared__ unsigned int wsum[4];
    __shared__ unsigned char cbin[N_];
    const int blk = blockIdx.x, t = threadIdx.x, lane = t & 63, wv = t >> 6;

    const bool isq = blk >= B_;
    const int b = isq ? blk - B_ : blk;
    const int cnt = isq ? N_ : S_;
    const float* xs = isq ? (xyz1 + (size_t)b*3*N_) : (xyz2 + (size_t)b*3*S_);

    if (t < NBX) h[t] = 0;
    __syncthreads();
    for (int s = t; s < cnt; s += 1024) {
        float x = xs[s];
        int bin = min(NBX-1, max(0, (int)floorf((x - XMIN_) * INVW_)));
        cbin[s] = (unsigned char)bin;
        atomicAdd(&h[bin], 1u);
    }
    __syncthreads();
    unsigned int v = 0, incl = 0;
    if (t < NBX) {                       // waves 0..3 fully active (uniform)
        v = h[t];
        incl = v;
        #pragma unroll
        for (int off = 1; off < 64; off <<= 1) {
            unsigned int u = __shfl_up(incl, off);
            if (lane >= off) incl += u;
        }
        if (lane == 63) wsum[wv] = incl;
    }
    __syncthreads();
    if (t < NBX) {
        unsigned int base = 0;
        for (int w = 0; w < wv; ++w) base += wsum[w];
        unsigned int excl = base + incl - v;
        h[t] = excl;
        if (!isq) {
            unsigned short* cum = wcum + (size_t)b * CUMP;
            cum[t] = (unsigned short)excl;
            if (t == 0) { cum[NBX] = (unsigned short)S_; cum[NBX+1] = (unsigned short)S_; }
        }
    }
    __syncthreads();
    if (!isq) {
        for (int s = t; s < S_; s += 1024) {
            unsigned int pos = atomicAdd(&h[cbin[s]], 1u);
            float bx = xs[s], by = xs[S_+s], bz = xs[2*S_+s];
            float nn = fmaf(bz, bz, fmaf(by, by, bx*bx));   // proven fma order
            wpts[(size_t)b*S_ + pos] = make_float4(-2.f*bx, -2.f*by, -2.f*bz, nn);
            wsid[(size_t)b*S_ + pos] = (unsigned short)s;
        }
    } else {
        for (int s = t; s < N_; s += 1024) {
            unsigned int pos = atomicAdd(&h[cbin[s]], 1u);
            wqid[(size_t)b*N_ + pos] = (unsigned short)s;
        }
    }
}

/* ------ one-shot slab exact 3-NN + interpolation (8 slots/query) ------- */
// (R7-proven structure + R9 two-chain ILP.) 2048 blocks x 256 thr. Wave =
// 8 sorted queries x 8 slots; lane = qi*8 + slot. Each lane runs TWO
// independent insert chains over disjoint j-parity sets (j, j+8 stride
// 16): two loads issue per iteration and the dependent insert chains
// interleave, halving exposed latency (the R8 post-mortem lever).
// Schedule: scan(window +-128 rank) -> probe d3ub (temp copies,
// discarded) -> slab = [cum[bin(ax-rad)], cum[bin(ax+rad)+1]) union over
// wave -> scan(slab \ window) -> merge chain B into A (in-lane, disjoint)
// -> single destructive slot butterfly. Exactness: unscanned candidate =>
// bin outside slab => |bx-ax| > rad => dist^2 > d3ub + 1e-3 (margin >>
// fma rounding) => cannot enter or tie into the top-3. idx = sorted
// position; remapped via wsid at the end.
__global__ __launch_bounds__(256, 4) void knn8_kernel(
    const float* __restrict__ xyz1,
    const float4* __restrict__ wpts,
    const unsigned short* __restrict__ wsid,
    const unsigned short* __restrict__ wcum,
    const unsigned short* __restrict__ wqid,
    const float* __restrict__ points2,
    float* __restrict__ out)
{
    __shared__ float s_w[3][QBLK];
    __shared__ int   s_idx[3][QBLK];
    __shared__ int   s_oq[QBLK];

    const int b    = blockIdx.x & 7;             // batch-per-XCD swizzle
    const int qblk = blockIdx.x >> 3;
    const int t = threadIdx.x;
    const int wave = t >> 6, wl = t & 63;
    const int qi = wl >> 3, slot = wl & 7;
    const int row = wave * QW + qi;              // 0..31 within block

    const unsigned short* cum = wcum + (size_t)b * CUMP;
    const int q = wqid[(size_t)b * N_ + qblk * QBLK + row];
    const float* x1 = xyz1 + (size_t)b*3*N_;
    const float ax = x1[q], ay = x1[N_+q], az = x1[2*N_+q];
    const float n1a = fmaf(az, az, fmaf(ay, ay, ax*ax));
    const int qbin = min(NBX-1, max(0, (int)floorf((ax - XMIN_)*INVW_)));
    const int cq = cum[qbin];

    // wave-uniform window around this wave's 8 queries
    int cmin = cq, cmax = cq;
    #pragma unroll
    for (int off = 1; off < 64; off <<= 1) {
        cmin = min(cmin, __shfl_xor(cmin, off));
        cmax = max(cmax, __shfl_xor(cmax, off));
    }
    const int wlo = __builtin_amdgcn_readfirstlane(max(cmin - 128, 0));
    const int whi = __builtin_amdgcn_readfirstlane(min(cmax + 128, S_));

    const float4* pts4 = wpts + (size_t)b * S_;
    // chain A and chain B: disjoint j sets, private per lane
    unsigned long long a0 = ~0ull, a1 = ~0ull, a2 = ~0ull;
    unsigned long long c0 = ~0ull, c1 = ~0ull, c2 = ~0ull;

    auto scan = [&](int j0, int j1) {
        int j = j0 + slot;
        #pragma unroll 2
        for (; j + 8 < j1; j += 16) {
            float4 pa = pts4[j];
            float4 pb = pts4[j + 8];
            float ka = fmaf(ax, pa.x, fmaf(ay, pa.y, fmaf(az, pa.z, pa.w)));
            float kb = fmaf(ax, pb.x, fmaf(ay, pb.y, fmaf(az, pb.z, pb.w)));
            ins3u64(packkey(ka, j),     a0, a1, a2);
            ins3u64(packkey(kb, j + 8), c0, c1, c2);
        }
        if (j < j1) {
            float4 pa = pts4[j];
            float ka = fmaf(ax, pa.x, fmaf(ay, pa.y, fmaf(az, pa.z, pa.w)));
            ins3u64(packkey(ka, j), a0, a1, a2);
        }
    };

    scan(wlo, whi);          // >=128 candidates seen by every query

    // ONE non-destructive probe: per-query d3 upper bound.
    // Temp copies: merge chain B copy into chain A copy (disjoint sets),
    // then slot butterfly (xor 1/2/4). All discarded after rad.
    unsigned long long r0 = a0, r1 = a1, r2 = a2;
    ins3u64(c0, r0, r1, r2);
    ins3u64(c1, r0, r1, r2);
    ins3u64(c2, r0, r1, r2);
    #pragma unroll
    for (int off = 1; off < 8; off <<= 1) {
        unsigned long long t0 = __shfl_xor(r0, off);
        unsigned long long t1 = __shfl_xor(r1, off);
        unsigned long long t2 = __shfl_xor(r2, off);
        ins3u64(t0, r0, r1, r2);
        ins3u64(t1, r0, r1, r2);
        ins3u64(t2, r0, r1, r2);
    }
    unsigned int sb2 = (unsigned int)(r2 >> 16);
    unsigned int kb2 = (sb2 & 0x80000000u) ? (sb2 ^ 0x80000000u) : ~sb2;
    float rad = sqrtf(fmaxf(__uint_as_float(kb2) + n1a + 1e-3f, 0.0f));
    int lob = min(NBX-1, max(0, (int)floorf((ax - rad - XMIN_)*INVW_)));
    int hib = min(NBX-1, max(0, (int)floorf((ax + rad - XMIN_)*INVW_)));
    int lo = cum[lob], hi = cum[hib + 1];

    // wave-uniform slab union
    int ulo = lo, uhi = hi;
    #pragma unroll
    for (int off = 1; off < 64; off <<= 1) {
        ulo = min(ulo, __shfl_xor(ulo, off));
        uhi = max(uhi, __shfl_xor(uhi, off));
    }
    ulo = __builtin_amdgcn_readfirstlane(ulo);
    uhi = __builtin_amdgcn_readfirstlane(uhi);

    // disjoint extensions (each j visited exactly once per query)
    scan(ulo, wlo);
    scan(whi, uhi);

    // merge chain B into A (in-lane, disjoint sets -> no duplicates)
    ins3u64(c0, a0, a1, a2);
    ins3u64(c1, a0, a1, a2);
    ins3u64(c2, a0, a1, a2);

    // single destructive slot butterfly (disjoint slot classes -> no dups)
    #pragma unroll
    for (int off = 1; off < 8; off <<= 1) {
        unsigned long long t0 = __shfl_xor(a0, off);
        unsigned long long t1 = __shfl_xor(a1, off);
        unsigned long long t2 = __shfl_xor(a2, off);
        ins3u64(t0, a0, a1, a2);
        ins3u64(t1, a0, a1, a2);
        ins3u64(t2, a0, a1, a2);
    }

    // epilogue: weights (proven arithmetic) + sorted-pos -> original id
    if (slot == 0) {
        const unsigned short* sid = wsid + (size_t)b * S_;
        unsigned int sb0 = (unsigned int)(a0 >> 16);
        unsigned int sb1 = (unsigned int)(a1 >> 16);
        unsigned int sb2b = (unsigned int)(a2 >> 16);
        float e0 = __uint_as_float((sb0 & 0x80000000u) ? (sb0 ^ 0x80000000u) : ~sb0);
        float e1 = __uint_as_float((sb1 & 0x80000000u) ? (sb1 ^ 0x80000000u) : ~sb1);
        float e2 = __uint_as_float((sb2b & 0x80000000u) ? (sb2b ^ 0x80000000u) : ~sb2b);
        float r0f = __fdiv_rn(1.0f, __fadd_rn(__fadd_rn(e0, n1a), EPS_));
        float r1f = __fdiv_rn(1.0f, __fadd_rn(__fadd_rn(e1, n1a), EPS_));
        float r2f = __fdiv_rn(1.0f, __fadd_rn(__fadd_rn(e2, n1a), EPS_));
        float rs = __fadd_rn(__fadd_rn(r0f, r1f), r2f);
        s_w[0][row] = __fdiv_rn(r0f, rs);
        s_w[1][row] = __fdiv_rn(r1f, rs);
        s_w[2][row] = __fdiv_rn(r2f, rs);
        s_idx[0][row] = sid[(int)(a0 & 0xFFFFu)];
        s_idx[1][row] = sid[(int)(a1 & 0xFFFFu)];
        s_idx[2][row] = sid[(int)(a2 & 0xFFFFu)];
        s_oq[row] = q;
    }
    __syncthreads();

    // phase C: gather + weighted sum; 32 rows, 4 waves, 64 lanes x float4
    const float* p2 = points2 + (size_t)b * S_ * D_;
    for (int r = wave; r < QBLK; r += 4) {
        float w0 = s_w[0][r], w1 = s_w[1][r], w2 = s_w[2][r];
        float* op = out + ((size_t)b*N_ + s_oq[r]) * D_;
        const float4* f0 = (const float4*)(p2 + (size_t)s_idx[0][r]*D_) + wl;
        const float4* f1 = (const float4*)(p2 + (size_t)s_idx[1][r]*D_) + wl;
        const float4* f2 = (const float4*)(p2 + (size_t)s_idx[2][r]*D_) + wl;
        float4 v0 = *f0, v1 = *f1, v2v = *f2;
        float4 r4;
        r4.x = w0*v0.x + w1*v1.x + w2*v2v.x;
        r4.y = w0*v0.y + w1*v1.y + w2*v2v.y;
        r4.z = w0*v0.z + w1*v1.z + w2*v2v.z;
        r4.w = w0*v0.w + w1*v1.w + w2*v2v.w;
        *((float4*)op + wl) = r4;
    }
}

/* ---------------- brute-force fallback (proven R2 path) ------------- */
__global__ __launch_bounds__(NTHR, 8) void fp_brute_kernel(
    const float* __restrict__ xyz1,
    const float* __restrict__ xyz2,
    const float* __restrict__ points2,
    float* __restrict__ out)
{
    __shared__ float s_nn[S_] __attribute__((aligned(16)));
    __shared__ float s_pd[NCH][3][TILE_Q];
    __shared__ int   s_pi[NCH][3][TILE_Q];
    __shared__ float s_w[3][TILE_Q];
    __shared__ int   s_idx[3][TILE_Q];

    const int b  = blockIdx.x & 7;
    const int n0 = (blockIdx.x >> 3) * TILE_Q;
    const int t = threadIdx.x;
    const int wave = t >> 6, lane = t & 63;

    const float* x2 = xyz2 + (size_t)b * 3 * S_;
    for (int s = t; s < S_; s += NTHR) {
        float bx = x2[s], by = x2[S_ + s], bz = x2[2 * S_ + s];
        s_nn[s] = fmaf(bz, bz, fmaf(by, by, bx * bx));
    }
    __syncthreads();

    const int n = n0 + lane;
    const float* x1 = xyz1 + (size_t)b * 3 * N_;
    const float ax = x1[n], ay = x1[N_ + n], az = x1[2 * N_ + n];
    const float ax2 = -2.0f * ax, ay2 = -2.0f * ay, az2 = -2.0f * az;

    float a0 = __builtin_inff(), a1 = __builtin_inff(), a2 = __builtin_inff();
    int ja0 = 0, ja1 = 0, ja2 = 0;
    float c0 = __builtin_inff(), c1 = __builtin_inff(), c2 = __builtin_inff();
    int jc0 = 0, jc1 = 0, jc2 = 0;

    const int wu   = __builtin_amdgcn_readfirstlane(wave);
    const int sbeg = wu * CHUNK;
    const float* bxp = x2;
    const float* byp = x2 + S_;
    const float* bzp = x2 + 2 * S_;
    const float4* nn4 = (const float4*)s_nn;
    const int g0 = sbeg >> 2;
    #pragma unroll 2
    for (int g = 0; g < HALF / 4; ++g) {
        float4 nl = nn4[g0 + g];
        float4 nh = nn4[g0 + (HALF >> 2) + g];
        #pragma unroll
        for (int u = 0; u < 4; ++u) {
            const int sl = sbeg + 4 * g + u;
            const int sh = sl + HALF;
            float kl = fmaf(ax2, bxp[sl],
                       fmaf(ay2, byp[sl], fmaf(az2, bzp[sl], (&nl.x)[u])));
            float kh = fmaf(ax2, bxp[sh],
                       fmaf(ay2, byp[sh], fmaf(az2, bzp[sh], (&nh.x)[u])));
            insert3(kl, sl, a0, a1, a2, ja0, ja1, ja2);
            insert3(kh, sh, c0, c1, c2, jc0, jc1, jc2);
        }
    }
    insert3(c0, jc0, a0, a1, a2, ja0, ja1, ja2);
    insert3(c1, jc1, a0, a1, a2, ja0, ja1, ja2);
    insert3(c2, jc2, a0, a1, a2, ja0, ja1, ja2);

    s_pd[wave][0][lane] = a0; s_pd[wave][1][lane] = a1; s_pd[wave][2][lane] = a2;
    s_pi[wave][0][lane] = ja0; s_pi[wave][1][lane] = ja1; s_pi[wave][2][lane] = ja2;
    __syncthreads();

    if (t < TILE_Q) {
        float e0 = __builtin_inff(), e1 = __builtin_inff(), e2 = __builtin_inff();
        int j0 = 0, j1 = 0, j2 = 0;
        #pragma unroll
        for (int c = 0; c < NCH; ++c)
            #pragma unroll
            for (int k = 0; k < 3; ++k)
                insert3(s_pd[c][k][t], s_pi[c][k][t], e0, e1, e2, j0, j1, j2);
        const int nq = n0 + t;
        float qx = x1[nq], qy = x1[N_ + nq], qz = x1[2 * N_ + nq];
        float n1 = fmaf(qz, qz, fmaf(qy, qy, qx * qx));
        float r0 = __fdiv_rn(1.0f, __fadd_rn(__fadd_rn(e0, n1), EPS_));
        float r1 = __fdiv_rn(1.0f, __fadd_rn(__fadd_rn(e1, n1), EPS_));
        float r2 = __fdiv_rn(1.0f, __fadd_rn(__fadd_rn(e2, n1), EPS_));
        float rs = __fadd_rn(__fadd_rn(r0, r1), r2);
        s_w[0][t] = __fdiv_rn(r0, rs);
        s_w[1][t] = __fdiv_rn(r1, rs);
        s_w[2][t] = __fdiv_rn(r2, rs);
        s_idx[0][t] = j0; s_idx[1][t] = j1; s_idx[2][t] = j2;
    }
    __syncthreads();

    const float* p2 = points2 + (size_t)b * S_ * D_;
    float* op = out + ((size_t)b * N_ + n0) * D_;
    for (int qq = wave; qq < TILE_Q; qq += NCH) {
        float w0 = s_w[0][qq], w1 = s_w[1][qq], w2 = s_w[2][qq];
        const float4* f0 = (const float4*)(p2 + (size_t)s_idx[0][qq] * D_) + lane;
        const float4* f1 = (const float4*)(p2 + (size_t)s_idx[1][qq] * D_) + lane;
        const float4* f2 = (const float4*)(p2 + (size_t)s_idx[2][qq] * D_) + lane;
        float4 v0 = *f0, v1 = *f1, v2 = *f2;
        float4 r;
        r.x = w0 * v0.x + w1 * v1.x + w2 * v2.x;
        r.y = w0 * v0.y + w1 * v1.y + w2 * v2.y;
        r.z = w0 * v0.z + w1 * v1.z + w2 * v2.z;
        r.w = w0 * v0.w + w1 * v1.w + w2 * v2.w;
        *((float4*)(op + (size_t)qq * D_) + lane) = r;
    }
}

extern "C" void kernel_launch(void* const* d_in, const int* in_sizes, int n_in,
                              void* d_out, int out_size, void* d_ws, size_t ws_size,
                              hipStream_t stream) {
    const float* xyz1    = (const float*)d_in[0];
    const float* xyz2    = (const float*)d_in[1];
    // d_in[2] = points1 is unused by the reference output.
    const float* points2 = (const float*)d_in[3];
    float* out = (float*)d_out;

    if (d_ws && ws_size >= (size_t)WS_NEED) {
        float4*         wpts = (float4*)d_ws;
        unsigned short* wsid = (unsigned short*)((char*)d_ws + WS_SID);
        unsigned short* wcum = (unsigned short*)((char*)d_ws + WS_CUM);
        unsigned short* wqid = (unsigned short*)((char*)d_ws + WS_QID);
        prep_sort_kernel<<<dim3(2*B_), dim3(1024), 0, stream>>>(
            xyz1, xyz2, wpts, wsid, wcum, wqid);
        knn8_kernel<<<dim3(B_ * (N_/QBLK)), dim3(256), 0, stream>>>(
            xyz1, wpts, wsid, wcum, wqid, points2, out);
    } else {
        fp_brute_kernel<<<dim3(B_ * (N_ / TILE_Q)), dim3(NTHR), 0, stream>>>(
            xyz1, xyz2, points2, out);
    }
}